// Round 4
// baseline (376.078 us; speedup 1.0000x reference)
//
#include <hip/hip_runtime.h>

#define BB 4
#define CC 256
#define NN 4096
#define DD 64

typedef _Float16 h8_t __attribute__((ext_vector_type(8)));
typedef _Float16 h4_t __attribute__((ext_vector_type(4)));
typedef float fx4 __attribute__((ext_vector_type(4)));

#define MFMA16(a, b, c) __builtin_amdgcn_mfma_f32_16x16x32_f16((a), (b), (c), 0, 0, 0)

// ---------------- K0: cast weights to f16, zero BN accumulators ----------------
__global__ __launch_bounds__(256) void k0_prep(
    const float* __restrict__ wq, const float* __restrict__ wv, const float* __restrict__ wt,
    _Float16* __restrict__ wqH, _Float16* __restrict__ wvH, _Float16* __restrict__ wtH,
    float* __restrict__ bnsum, float* __restrict__ bnsumsq) {
  int i = blockIdx.x * 256 + threadIdx.x;
  int stride = gridDim.x * 256;
  for (int j = i; j < DD * CC; j += stride) wqH[j] = (_Float16)wq[j];
  for (int j = i; j < CC * CC; j += stride) wvH[j] = (_Float16)wv[j];
  for (int j = i; j < CC * CC; j += stride) wtH[j] = (_Float16)wt[j];
  if (i < CC) { bnsum[i] = 0.f; bnsumsq[i] = 0.f; }
}

// ---------------- K1a: transpose-cast x [b][c][n] f32 -> xt [b][n][c] f16 ------
__global__ __launch_bounds__(256) void k1a_transpose(const float* __restrict__ x,
                                                     _Float16* __restrict__ xt) {
  __shared__ float tile[32][33];
  int b = blockIdx.z;
  int c0 = blockIdx.y * 32, n0 = blockIdx.x * 32;
  int t = threadIdx.x;
  int tn = t & 31, tc = t >> 5;
  const float* xb = x + (size_t)b * CC * NN;
#pragma unroll
  for (int i = 0; i < 4; i++) {
    int c = tc + i * 8;
    tile[c][tn] = xb[(size_t)(c0 + c) * NN + n0 + tn];
  }
  __syncthreads();
  _Float16* xtb = xt + (size_t)b * NN * CC;
#pragma unroll
  for (int i = 0; i < 4; i++) {
    int n = tc + i * 8;
    xtb[(size_t)(n0 + n) * CC + c0 + tn] = (_Float16)tile[tn][n];
  }
}

// ---------------- K1b: projections Q = wq@x, V = wv@x + bv (f16 MFMA) ----------
__global__ __launch_bounds__(256, 2) void k1b_proj(
    const _Float16* __restrict__ xt, const _Float16* __restrict__ wqH,
    const _Float16* __restrict__ wvH, const float* __restrict__ bv,
    _Float16* __restrict__ qh, _Float16* __restrict__ vh) {
  int L = blockIdx.x;
  int xcd = L & 7, j = L >> 3;
  int b = xcd >> 1;
  int nB = ((xcd & 1) * 64 + j) * 32;
  int w = threadIdx.x >> 6, lane = threadIdx.x & 63;
  int g = lane >> 4, q = lane & 15;
  int wsub = w & 1, h = w >> 1;
  int n = nB + wsub * 16 + q;
  const _Float16* xr = xt + ((size_t)b * NN + n) * CC;
  fx4 accQ[4] = {};
  fx4 accV[8] = {};
  for (int kt = 0; kt < 8; kt++) {
    h8_t bf = *(const h8_t*)(xr + kt * 32 + g * 8);
    if (h == 0) {
#pragma unroll
      for (int ot = 0; ot < 4; ot++) {
        h8_t a = *(const h8_t*)(wqH + (size_t)(ot * 16 + q) * CC + kt * 32 + g * 8);
        accQ[ot] = MFMA16(a, bf, accQ[ot]);
      }
    }
#pragma unroll
    for (int ot = 0; ot < 8; ot++) {
      int o16 = h * 8 + ot;
      h8_t a = *(const h8_t*)(wvH + (size_t)(o16 * 16 + q) * CC + kt * 32 + g * 8);
      accV[ot] = MFMA16(a, bf, accV[ot]);
    }
  }
  if (h == 0) {
    _Float16* qr = qh + ((size_t)b * NN + n) * DD;
#pragma unroll
    for (int ot = 0; ot < 4; ot++) {
      h4_t hq;
#pragma unroll
      for (int r = 0; r < 4; r++) hq[r] = (_Float16)accQ[ot][r];
      *(h4_t*)(qr + ot * 16 + g * 4) = hq;
    }
  }
#pragma unroll
  for (int ot = 0; ot < 8; ot++) {
#pragma unroll
    for (int r = 0; r < 4; r++) {
      int o = (h * 8 + ot) * 16 + g * 4 + r;
      vh[((size_t)b * CC + o) * NN + n] = (_Float16)(accV[ot][r] + bv[o]);
    }
  }
}

// ---------------- K2: rowmax + rowsuminv, m-tile 32, grid 512 ------------------
__global__ __launch_bounds__(512, 4) void k2_stats(
    const _Float16* __restrict__ qh, float* __restrict__ rowmax,
    float* __restrict__ rowsuminv) {
  __shared__ float redb[8][32];
  __shared__ float rmS[32];
  int L = blockIdx.x;
  int xcd = L & 7;
  int b = xcd >> 1;
  int mi = (L & 1) * 64 + (L >> 3);
  int mB = mi * 32;
  int w = threadIdx.x >> 6, lane = threadIdx.x & 63;
  int g = lane >> 4, q = lane & 15;
  const _Float16* qb = qh + (size_t)b * NN * DD;
  h8_t aq[2][2];
#pragma unroll
  for (int mt = 0; mt < 2; mt++) {
    aq[mt][0] = *(const h8_t*)(qb + (size_t)(mB + mt * 16 + q) * DD + g * 8);
    aq[mt][1] = *(const h8_t*)(qb + (size_t)(mB + mt * 16 + q) * DD + 32 + g * 8);
  }
  fx4 rmax[2];
#pragma unroll
  for (int mt = 0; mt < 2; mt++)
#pragma unroll
    for (int r = 0; r < 4; r++) rmax[mt][r] = -1e30f;
  for (int ch = 0; ch < 32; ch++) {
    int n0 = ch * 128 + w * 16;
    h8_t b0 = *(const h8_t*)(qb + (size_t)(n0 + q) * DD + g * 8);
    h8_t b1 = *(const h8_t*)(qb + (size_t)(n0 + q) * DD + 32 + g * 8);
#pragma unroll
    for (int mt = 0; mt < 2; mt++) {
      fx4 e = {};
      e = MFMA16(aq[mt][0], b0, e);
      e = MFMA16(aq[mt][1], b1, e);
#pragma unroll
      for (int r = 0; r < 4; r++) rmax[mt][r] = fmaxf(rmax[mt][r], e[r]);
    }
  }
#pragma unroll
  for (int off = 1; off < 16; off <<= 1)
#pragma unroll
    for (int mt = 0; mt < 2; mt++)
#pragma unroll
      for (int r = 0; r < 4; r++)
        rmax[mt][r] = fmaxf(rmax[mt][r], __shfl_xor(rmax[mt][r], off));
  if (q == 0) {
#pragma unroll
    for (int mt = 0; mt < 2; mt++)
#pragma unroll
      for (int r = 0; r < 4; r++) redb[w][mt * 16 + g * 4 + r] = rmax[mt][r];
  }
  __syncthreads();
  if (threadIdx.x < 32) {
    float M = redb[0][threadIdx.x];
#pragma unroll
    for (int w2 = 1; w2 < 8; w2++) M = fmaxf(M, redb[w2][threadIdx.x]);
    rmS[threadIdx.x] = M;
    rowmax[b * NN + mB + threadIdx.x] = M;
  }
  __syncthreads();
  float rmv[2][4];
#pragma unroll
  for (int mt = 0; mt < 2; mt++)
#pragma unroll
    for (int r = 0; r < 4; r++) rmv[mt][r] = rmS[mt * 16 + g * 4 + r];
  fx4 s[2] = {};
  for (int ch = 0; ch < 32; ch++) {
    int n0 = ch * 128 + w * 16;
    h8_t b0 = *(const h8_t*)(qb + (size_t)(n0 + q) * DD + g * 8);
    h8_t b1 = *(const h8_t*)(qb + (size_t)(n0 + q) * DD + 32 + g * 8);
#pragma unroll
    for (int mt = 0; mt < 2; mt++) {
      fx4 e = {};
      e = MFMA16(aq[mt][0], b0, e);
      e = MFMA16(aq[mt][1], b1, e);
#pragma unroll
      for (int r = 0; r < 4; r++) s[mt][r] += __expf(e[r] - rmv[mt][r]);
    }
  }
#pragma unroll
  for (int off = 1; off < 16; off <<= 1)
#pragma unroll
    for (int mt = 0; mt < 2; mt++)
#pragma unroll
      for (int r = 0; r < 4; r++) s[mt][r] += __shfl_xor(s[mt][r], off);
  if (q == 0) {
#pragma unroll
    for (int mt = 0; mt < 2; mt++)
#pragma unroll
      for (int r = 0; r < 4; r++) redb[w][mt * 16 + g * 4 + r] = s[mt][r];
  }
  __syncthreads();
  if (threadIdx.x < 32) {
    float S = redb[0][threadIdx.x];
#pragma unroll
    for (int w2 = 1; w2 < 8; w2++) S += redb[w2][threadIdx.x];
    rowsuminv[b * NN + mB + threadIdx.x] = 1.f / S;
  }
}

// ---------------- K4: m-tile 32, 16 phases x 256 n, dbuf P, 2 blocks/CU --------
#define PSTR 264  // P/xdT row stride in f16 (256 data + 8 pad)
__global__ __launch_bounds__(512, 4) void k4_main(
    const _Float16* __restrict__ qh, const _Float16* __restrict__ vh,
    const _Float16* __restrict__ wtH, const float* __restrict__ rowmax,
    const float* __restrict__ rowsuminv, const _Float16* __restrict__ xt,
    const float* __restrict__ bt, _Float16* __restrict__ th,
    float* __restrict__ bnsum, float* __restrict__ bnsumsq) {
  __shared__ _Float16 Pb[2][32 * PSTR];  // [m_local 32][n_local 256]
  __shared__ _Float16 xdT[32 * PSTR];    // [m_local 32][c 256]
  __shared__ float csLDS[8][32];
  __shared__ float csT[32];
  int L = blockIdx.x;
  int xcd = L & 7;
  int b = xcd >> 1;
  int mi = (L & 1) * 64 + (L >> 3);
  int mB = mi * 32;
  int w = threadIdx.x >> 6, lane = threadIdx.x & 63;
  int g = lane >> 4, q = lane & 15;
  const _Float16* qb = qh + (size_t)b * NN * DD;
  const _Float16* vb = vh + (size_t)b * CC * NN;
  const float* rm = rowmax + b * NN;
  const float* ri = rowsuminv + b * NN;

  // persistent Q fragments (B-operand rows = this block's m columns)
  h8_t aq[2][2];
#pragma unroll
  for (int mt = 0; mt < 2; mt++) {
    aq[mt][0] = *(const h8_t*)(qb + (size_t)(mB + mt * 16 + q) * DD + g * 8);
    aq[mt][1] = *(const h8_t*)(qb + (size_t)(mB + mt * 16 + q) * DD + 32 + g * 8);
  }

  float csum[2] = {0.f, 0.f};
  h8_t pa0[2], pa1[2];  // K rows for the phase being built (2 sub-chunks of 128)

  auto loadK = [&](int ph) {
#pragma unroll
    for (int sc = 0; sc < 2; sc++) {
      int n0 = ph * 256 + sc * 128 + w * 16;
      pa0[sc] = *(const h8_t*)(qb + (size_t)(n0 + q) * DD + g * 8);
      pa1[sc] = *(const h8_t*)(qb + (size_t)(n0 + q) * DD + 32 + g * 8);
    }
  };
  // build P[n_local][m_local] for one 256-n phase into Pb[nb]
  auto buildP = [&](int ph, int nb) {
#pragma unroll
    for (int sc = 0; sc < 2; sc++) {
      int n0 = ph * 256 + sc * 128 + w * 16;
      fx4 rmv = *(const fx4*)(rm + n0 + 4 * g);
      fx4 riv = *(const fx4*)(ri + n0 + 4 * g);
#pragma unroll
      for (int mt = 0; mt < 2; mt++) {
        fx4 e = {};
        e = MFMA16(pa0[sc], aq[mt][0], e);
        e = MFMA16(pa1[sc], aq[mt][1], e);
        h4_t p;
        float sacc = 0.f;
#pragma unroll
        for (int r = 0; r < 4; r++) {
          float pv = __expf(e[r] - rmv[r]) * riv[r];
          p[r] = (_Float16)pv;
          sacc += pv;
        }
        csum[mt] += sacc;
        *(h4_t*)&Pb[nb][(mt * 16 + q) * PSTR + sc * 128 + w * 16 + 4 * g] = p;
      }
    }
  };

  // prologue
  loadK(0);
  buildP(0, 0);
  loadK(1);
  __syncthreads();

  fx4 acc[2][2] = {};  // [ct][mt]
  for (int ph = 0; ph < 16; ph++) {
    int cur = ph & 1;
    // preload V for this phase (4-deep rolling, 2 c-rows per wave)
    const _Float16* vr0 = vb + (size_t)(32 * w + q) * NN + ph * 256;
    const _Float16* vr1 = vb + (size_t)(32 * w + 16 + q) * NN + ph * 256;
    h8_t av0[4], av1[4];
#pragma unroll
    for (int p0 = 0; p0 < 4; p0++) {
      av0[p0] = *(const h8_t*)(vr0 + p0 * 32 + g * 8);
      av1[p0] = *(const h8_t*)(vr1 + p0 * 32 + g * 8);
    }
    // build next phase's P (uses K rows loaded one phase ago), then refill K regs
    if (ph < 15) buildP(ph + 1, cur ^ 1);
    if (ph < 14) loadK(ph + 2);
    // V-GEMM over 256 n
#pragma unroll
    for (int kt = 0; kt < 8; kt++) {
      int pp = kt & 3;
      h8_t bp0 = *(const h8_t*)&Pb[cur][q * PSTR + kt * 32 + g * 8];
      h8_t bp1 = *(const h8_t*)&Pb[cur][(16 + q) * PSTR + kt * 32 + g * 8];
      acc[0][0] = MFMA16(av0[pp], bp0, acc[0][0]);
      acc[0][1] = MFMA16(av0[pp], bp1, acc[0][1]);
      acc[1][0] = MFMA16(av1[pp], bp0, acc[1][0]);
      acc[1][1] = MFMA16(av1[pp], bp1, acc[1][1]);
      if (kt < 4) {
        av0[pp] = *(const h8_t*)(vr0 + (kt + 4) * 32 + g * 8);
        av1[pp] = *(const h8_t*)(vr1 + (kt + 4) * 32 + g * 8);
      }
    }
    __syncthreads();
  }

  // colsum reduce: csum[mt] is partial for m = mB + mt*16 + q over this lane's n
#pragma unroll
  for (int mt = 0; mt < 2; mt++) {
    float cs = csum[mt];
    cs += __shfl_xor(cs, 16);
    cs += __shfl_xor(cs, 32);
    if (lane < 16) csLDS[w][mt * 16 + q] = cs;
  }
  __syncthreads();
  if (threadIdx.x < 32) {
    float s = 0.f;
#pragma unroll
    for (int w2 = 0; w2 < 8; w2++) s += csLDS[w2][threadIdx.x];
    csT[threadIdx.x] = 1.f / (1e-9f + s);
  }
  __syncthreads();
  float cinv[2] = {csT[q], csT[16 + q]};

  // epilogue: x_d = x - x_a  -> xdT
#pragma unroll
  for (int ct = 0; ct < 2; ct++) {
#pragma unroll
    for (int mt = 0; mt < 2; mt++) {
      h4_t xv = *(const h4_t*)(xt + ((size_t)b * NN + mB + mt * 16 + q) * CC + 32 * w + ct * 16 + 4 * g);
      h4_t hd;
#pragma unroll
      for (int r = 0; r < 4; r++) {
        float xd = (float)xv[r] - acc[ct][mt][r] * cinv[mt];
        hd[r] = (_Float16)xd;
      }
      *(h4_t*)&xdT[(mt * 16 + q) * PSTR + 32 * w + ct * 16 + 4 * g] = hd;
    }
  }
  __syncthreads();

  // t = wt @ x_d + bt
  fx4 acct[2][2] = {};
  for (int kt = 0; kt < 8; kt++) {
    h8_t bx0 = *(const h8_t*)&xdT[q * PSTR + kt * 32 + g * 8];
    h8_t bx1 = *(const h8_t*)&xdT[(16 + q) * PSTR + kt * 32 + g * 8];
#pragma unroll
    for (int ot = 0; ot < 2; ot++) {
      h8_t a = *(const h8_t*)(wtH + (size_t)(32 * w + ot * 16 + q) * CC + kt * 32 + g * 8);
      acct[ot][0] = MFMA16(a, bx0, acct[ot][0]);
      acct[ot][1] = MFMA16(a, bx1, acct[ot][1]);
    }
  }
#pragma unroll
  for (int ot = 0; ot < 2; ot++) {
#pragma unroll
    for (int r = 0; r < 4; r++) {
      int o = 32 * w + ot * 16 + 4 * g + r;
      float btv = bt[o];
      float t0 = acct[ot][0][r] + btv;
      float t1 = acct[ot][1][r] + btv;
      th[((size_t)b * CC + o) * NN + mB + q] = (_Float16)t0;
      th[((size_t)b * CC + o) * NN + mB + 16 + q] = (_Float16)t1;
      float s1 = t0 + t1, s2 = t0 * t0 + t1 * t1;
#pragma unroll
      for (int off = 1; off < 16; off <<= 1) {
        s1 += __shfl_xor(s1, off);
        s2 += __shfl_xor(s2, off);
      }
      if (q == 0) {
        atomicAdd(&bnsum[o], s1);
        atomicAdd(&bnsumsq[o], s2);
      }
    }
  }
}

// ---------------- K6: BN finalize (folded) + out = x + relu(sc*t + sh) ---------
__global__ __launch_bounds__(256) void k6_final(
    const float* __restrict__ x, const _Float16* __restrict__ th,
    const float* __restrict__ bnsum, const float* __restrict__ bnsumsq,
    const float* __restrict__ gamma, const float* __restrict__ beta,
    float* __restrict__ out) {
  size_t i = (size_t)blockIdx.x * 256 + threadIdx.x;
  size_t base = i * 8;
  int c = (int)((base >> 12) & 255);
  float inv = 1.f / (float)(BB * NN);
  float mean = bnsum[c] * inv;
  float var = bnsumsq[c] * inv - mean * mean;
  float sc = gamma[c] * rsqrtf(var + 1e-5f);
  float sh = beta[c] - mean * sc;
  h8_t t8 = *(const h8_t*)(th + base);
  fx4 x0 = *(const fx4*)(x + base);
  fx4 x1 = *(const fx4*)(x + base + 4);
  fx4 o0, o1;
#pragma unroll
  for (int j2 = 0; j2 < 4; j2++) {
    o0[j2] = x0[j2] + fmaxf(0.f, sc * (float)t8[j2] + sh);
    o1[j2] = x1[j2] + fmaxf(0.f, sc * (float)t8[j2 + 4] + sh);
  }
  *(fx4*)(out + base) = o0;
  *(fx4*)(out + base + 4) = o1;
}

extern "C" void kernel_launch(void* const* d_in, const int* in_sizes, int n_in,
                              void* d_out, int out_size, void* d_ws, size_t ws_size,
                              hipStream_t stream) {
  const float* x = (const float*)d_in[0];
  const float* wq = (const float*)d_in[1];
  const float* wv = (const float*)d_in[2];
  const float* bv = (const float*)d_in[3];
  const float* wt = (const float*)d_in[4];
  const float* bt = (const float*)d_in[5];
  const float* gamma = (const float*)d_in[6];
  const float* beta = (const float*)d_in[7];
  char* ws = (char*)d_ws;
  _Float16* qh = (_Float16*)(ws + 0);            // 2 MB
  _Float16* vh = (_Float16*)(ws + 2097152);      // 8 MB
  _Float16* xt = (_Float16*)(ws + 10485760);     // 8 MB
  _Float16* wqH = (_Float16*)(ws + 18874368);    // 32 KB
  _Float16* wvH = (_Float16*)(ws + 18907136);    // 128 KB
  _Float16* wtH = (_Float16*)(ws + 19038208);    // 128 KB
  float* rowmax = (float*)(ws + 19169280);       // 64 KB
  float* rowsuminv = (float*)(ws + 19234816);    // 64 KB
  float* bnsum = (float*)(ws + 19365888);        // 1 KB
  float* bnsumsq = (float*)(ws + 19366912);      // 1 KB
  _Float16* th = (_Float16*)(ws + 19369984);     // 8 MB

  hipLaunchKernelGGL(k0_prep, dim3(64), dim3(256), 0, stream,
                     wq, wv, wt, wqH, wvH, wtH, bnsum, bnsumsq);
  hipLaunchKernelGGL(k1a_transpose, dim3(128, 8, 4), dim3(256), 0, stream, x, xt);
  hipLaunchKernelGGL(k1b_proj, dim3(512), dim3(256), 0, stream, xt, wqH, wvH, bv, qh, vh);
  hipLaunchKernelGGL(k2_stats, dim3(512), dim3(512), 0, stream, qh, rowmax, rowsuminv);
  hipLaunchKernelGGL(k4_main, dim3(512), dim3(512), 0, stream, qh, vh, wtH,
                     rowmax, rowsuminv, xt, bt, th, bnsum, bnsumsq);
  hipLaunchKernelGGL(k6_final, dim3(2048), dim3(256), 0, stream,
                     x, th, bnsum, bnsumsq, gamma, beta, (float*)d_out);
}

// Round 6
// 370.427 us; speedup vs baseline: 1.0153x; 1.0153x over previous
//
#include <hip/hip_runtime.h>

#define BB 4
#define CC 256
#define NN 4096
#define DD 64

typedef _Float16 h8_t __attribute__((ext_vector_type(8)));
typedef _Float16 h4_t __attribute__((ext_vector_type(4)));
typedef float fx4 __attribute__((ext_vector_type(4)));

#define MFMA16(a, b, c) __builtin_amdgcn_mfma_f32_16x16x32_f16((a), (b), (c), 0, 0, 0)

#define GLOAD16(g, l)                                                          \
  __builtin_amdgcn_global_load_lds(                                            \
      (const __attribute__((address_space(1))) unsigned int*)(g),              \
      (__attribute__((address_space(3))) unsigned int*)(l), 16, 0, 0)

// ---------------- K0: cast weights to f16, zero accumulators -------------------
__global__ __launch_bounds__(256) void k0_prep(
    const float* __restrict__ wq, const float* __restrict__ wv, const float* __restrict__ wt,
    _Float16* __restrict__ wqH, _Float16* __restrict__ wvH, _Float16* __restrict__ wtH,
    float* __restrict__ bnsum, float* __restrict__ bnsumsq, float* __restrict__ colsum) {
  int i = blockIdx.x * 256 + threadIdx.x;
  int stride = gridDim.x * 256;
  for (int j = i; j < DD * CC; j += stride) wqH[j] = (_Float16)wq[j];
  for (int j = i; j < CC * CC; j += stride) wvH[j] = (_Float16)wv[j];
  for (int j = i; j < CC * CC; j += stride) wtH[j] = (_Float16)wt[j];
  if (i < CC) { bnsum[i] = 0.f; bnsumsq[i] = 0.f; }
  if (i < BB * NN) colsum[i] = 0.f;
}

// ---------------- K1a: transpose-cast x [b][c][n] f32 -> xt [b][n][c] f16 ------
__global__ __launch_bounds__(256) void k1a_transpose(const float* __restrict__ x,
                                                     _Float16* __restrict__ xt) {
  __shared__ float tile[32][33];
  int b = blockIdx.z;
  int c0 = blockIdx.y * 32, n0 = blockIdx.x * 32;
  int t = threadIdx.x;
  int tn = t & 31, tc = t >> 5;
  const float* xb = x + (size_t)b * CC * NN;
#pragma unroll
  for (int i = 0; i < 4; i++) {
    int c = tc + i * 8;
    tile[c][tn] = xb[(size_t)(c0 + c) * NN + n0 + tn];
  }
  __syncthreads();
  _Float16* xtb = xt + (size_t)b * NN * CC;
#pragma unroll
  for (int i = 0; i < 4; i++) {
    int n = tc + i * 8;
    xtb[(size_t)(n0 + n) * CC + c0 + tn] = (_Float16)tile[tn][n];
  }
}

// ---------------- K1b: Q = wq@x, V = wv@x + bv (V stored col-swizzled) ---------
__global__ __launch_bounds__(256, 2) void k1b_proj(
    const _Float16* __restrict__ xt, const _Float16* __restrict__ wqH,
    const _Float16* __restrict__ wvH, const float* __restrict__ bv,
    _Float16* __restrict__ qh, _Float16* __restrict__ vh) {
  int L = blockIdx.x;
  int xcd = L & 7, j = L >> 3;
  int b = xcd >> 1;
  int nB = ((xcd & 1) * 64 + j) * 32;
  int w = threadIdx.x >> 6, lane = threadIdx.x & 63;
  int g = lane >> 4, q = lane & 15;
  int wsub = w & 1, h = w >> 1;
  int n = nB + wsub * 16 + q;
  const _Float16* xr = xt + ((size_t)b * NN + n) * CC;
  fx4 accQ[4] = {};
  fx4 accV[8] = {};
  for (int kt = 0; kt < 8; kt++) {
    h8_t bf = *(const h8_t*)(xr + kt * 32 + g * 8);
    if (h == 0) {
#pragma unroll
      for (int ot = 0; ot < 4; ot++) {
        h8_t a = *(const h8_t*)(wqH + (size_t)(ot * 16 + q) * CC + kt * 32 + g * 8);
        accQ[ot] = MFMA16(a, bf, accQ[ot]);
      }
    }
#pragma unroll
    for (int ot = 0; ot < 8; ot++) {
      int o16 = h * 8 + ot;
      h8_t a = *(const h8_t*)(wvH + (size_t)(o16 * 16 + q) * CC + kt * 32 + g * 8);
      accV[ot] = MFMA16(a, bf, accV[ot]);
    }
  }
  if (h == 0) {
    _Float16* qr = qh + ((size_t)b * NN + n) * DD;
#pragma unroll
    for (int ot = 0; ot < 4; ot++) {
      h4_t hq;
#pragma unroll
      for (int r = 0; r < 4; r++) hq[r] = (_Float16)accQ[ot][r];
      *(h4_t*)(qr + ot * 16 + g * 4) = hq;
    }
  }
#pragma unroll
  for (int ot = 0; ot < 8; ot++) {
#pragma unroll
    for (int r = 0; r < 4; r++) {
      int o = (h * 8 + ot) * 16 + g * 4 + r;
      // XOR-swizzled column within each 64-wide chunk (T2, pre-applied in global)
      int nsw = (n & ~63) | ((((n >> 3) & 7) ^ (o & 7)) << 3) | (n & 7);
      vh[((size_t)b * CC + o) * NN + nsw] = (_Float16)(accV[ot][r] + bv[o]);
    }
  }
}

// ---------------- K2: rowmax + rowsuminv, m-tile 32, grid 512 ------------------
__global__ __launch_bounds__(512, 4) void k2_stats(
    const _Float16* __restrict__ qh, float* __restrict__ rowmax,
    float* __restrict__ rowsuminv) {
  __shared__ float redb[8][32];
  __shared__ float rmS[32];
  int L = blockIdx.x;
  int xcd = L & 7;
  int b = xcd >> 1;
  int mi = (L & 1) * 64 + (L >> 3);
  int mB = mi * 32;
  int w = threadIdx.x >> 6, lane = threadIdx.x & 63;
  int g = lane >> 4, q = lane & 15;
  const _Float16* qb = qh + (size_t)b * NN * DD;
  h8_t aq[2][2];
#pragma unroll
  for (int mt = 0; mt < 2; mt++) {
    aq[mt][0] = *(const h8_t*)(qb + (size_t)(mB + mt * 16 + q) * DD + g * 8);
    aq[mt][1] = *(const h8_t*)(qb + (size_t)(mB + mt * 16 + q) * DD + 32 + g * 8);
  }
  fx4 rmax[2];
#pragma unroll
  for (int mt = 0; mt < 2; mt++)
#pragma unroll
    for (int r = 0; r < 4; r++) rmax[mt][r] = -1e30f;
  for (int ch = 0; ch < 32; ch++) {
    int n0 = ch * 128 + w * 16;
    h8_t b0 = *(const h8_t*)(qb + (size_t)(n0 + q) * DD + g * 8);
    h8_t b1 = *(const h8_t*)(qb + (size_t)(n0 + q) * DD + 32 + g * 8);
#pragma unroll
    for (int mt = 0; mt < 2; mt++) {
      fx4 e = {};
      e = MFMA16(aq[mt][0], b0, e);
      e = MFMA16(aq[mt][1], b1, e);
#pragma unroll
      for (int r = 0; r < 4; r++) rmax[mt][r] = fmaxf(rmax[mt][r], e[r]);
    }
  }
#pragma unroll
  for (int off = 1; off < 16; off <<= 1)
#pragma unroll
    for (int mt = 0; mt < 2; mt++)
#pragma unroll
      for (int r = 0; r < 4; r++)
        rmax[mt][r] = fmaxf(rmax[mt][r], __shfl_xor(rmax[mt][r], off));
  if (q == 0) {
#pragma unroll
    for (int mt = 0; mt < 2; mt++)
#pragma unroll
      for (int r = 0; r < 4; r++) redb[w][mt * 16 + g * 4 + r] = rmax[mt][r];
  }
  __syncthreads();
  if (threadIdx.x < 32) {
    float M = redb[0][threadIdx.x];
#pragma unroll
    for (int w2 = 1; w2 < 8; w2++) M = fmaxf(M, redb[w2][threadIdx.x]);
    rmS[threadIdx.x] = M;
    rowmax[b * NN + mB + threadIdx.x] = M;
  }
  __syncthreads();
  float rmv[2][4];
#pragma unroll
  for (int mt = 0; mt < 2; mt++)
#pragma unroll
    for (int r = 0; r < 4; r++) rmv[mt][r] = rmS[mt * 16 + g * 4 + r];
  fx4 s[2] = {};
  for (int ch = 0; ch < 32; ch++) {
    int n0 = ch * 128 + w * 16;
    h8_t b0 = *(const h8_t*)(qb + (size_t)(n0 + q) * DD + g * 8);
    h8_t b1 = *(const h8_t*)(qb + (size_t)(n0 + q) * DD + 32 + g * 8);
#pragma unroll
    for (int mt = 0; mt < 2; mt++) {
      fx4 e = {};
      e = MFMA16(aq[mt][0], b0, e);
      e = MFMA16(aq[mt][1], b1, e);
#pragma unroll
      for (int r = 0; r < 4; r++) s[mt][r] += __expf(e[r] - rmv[mt][r]);
    }
  }
#pragma unroll
  for (int off = 1; off < 16; off <<= 1)
#pragma unroll
    for (int mt = 0; mt < 2; mt++)
#pragma unroll
      for (int r = 0; r < 4; r++) s[mt][r] += __shfl_xor(s[mt][r], off);
  if (q == 0) {
#pragma unroll
    for (int mt = 0; mt < 2; mt++)
#pragma unroll
      for (int r = 0; r < 4; r++) redb[w][mt * 16 + g * 4 + r] = s[mt][r];
  }
  __syncthreads();
  if (threadIdx.x < 32) {
    float S = redb[0][threadIdx.x];
#pragma unroll
    for (int w2 = 1; w2 < 8; w2++) S += redb[w2][threadIdx.x];
    rowsuminv[b * NN + mB + threadIdx.x] = 1.f / S;
  }
}

// ---------------- K3: P materialization, PT[b][m][n] (col-swizzled) + colsum ---
__global__ __launch_bounds__(512, 2) void k3_pmat(
    const _Float16* __restrict__ qh, const float* __restrict__ rowmax,
    const float* __restrict__ rowsuminv, _Float16* __restrict__ PT,
    float* __restrict__ colsum) {
  int nB = blockIdx.x * 128, mB = blockIdx.y * 128, b = blockIdx.z;
  int w = threadIdx.x >> 6, lane = threadIdx.x & 63;
  int g = lane >> 4, q = lane & 15;
  int iw = w >> 2, jw = w & 3;  // i(n): 2x64, j(m): 4x32
  const _Float16* qb = qh + (size_t)b * NN * DD;
  const float* rm = rowmax + b * NN;
  const float* ri = rowsuminv + b * NN;
  h8_t af[4][2], bf[2][2];
#pragma unroll
  for (int it = 0; it < 4; it++) {
    int nr = nB + iw * 64 + it * 16 + q;
#pragma unroll
    for (int kt = 0; kt < 2; kt++)
      af[it][kt] = *(const h8_t*)(qb + (size_t)nr * DD + kt * 32 + g * 8);
  }
#pragma unroll
  for (int jt = 0; jt < 2; jt++) {
    int mr = mB + jw * 32 + jt * 16 + q;
#pragma unroll
    for (int kt = 0; kt < 2; kt++)
      bf[jt][kt] = *(const h8_t*)(qb + (size_t)mr * DD + kt * 32 + g * 8);
  }
  float cs[2] = {0.f, 0.f};
#pragma unroll
  for (int it = 0; it < 4; it++) {
    int n4 = nB + iw * 64 + it * 16 + 4 * g;
    fx4 rmv = *(const fx4*)(rm + n4);
    fx4 riv = *(const fx4*)(ri + n4);
#pragma unroll
    for (int jt = 0; jt < 2; jt++) {
      fx4 e = {};
      e = MFMA16(af[it][0], bf[jt][0], e);
      e = MFMA16(af[it][1], bf[jt][1], e);
      int m = mB + jw * 32 + jt * 16 + q;
      h4_t p;
      float sacc = 0.f;
#pragma unroll
      for (int r = 0; r < 4; r++) {
        float pv = __expf(e[r] - rmv[r]) * riv[r];
        p[r] = (_Float16)pv;
        sacc += pv;
      }
      cs[jt] += sacc;
      int nsw = (n4 & ~63) | ((((n4 >> 3) & 7) ^ (m & 7)) << 3) | (n4 & 7);
      *(h4_t*)&PT[((size_t)b * NN + m) * NN + nsw] = p;
    }
  }
#pragma unroll
  for (int jt = 0; jt < 2; jt++) {
    float s = cs[jt];
    s += __shfl_xor(s, 16);
    s += __shfl_xor(s, 32);
    if (lane < 16)
      atomicAdd(&colsum[b * NN + mB + jw * 32 + jt * 16 + q], s);
  }
}

// ---------------- K4: x_a = V@P (m97-style GEMM) + x_d epilogue ----------------
// tile: 128 c x 64 m, BK=64, dbuf LDS, grid 2x64x4 = 512 (2 blocks/CU)
__global__ __launch_bounds__(256, 2) void k4_pv(
    const _Float16* __restrict__ vh, const _Float16* __restrict__ PT,
    const float* __restrict__ colsum, const float* __restrict__ x,
    _Float16* __restrict__ xdT) {
  __shared__ _Float16 Vt[2][128 * 64];
  __shared__ _Float16 Pt[2][64 * 64];
  int c0 = blockIdx.x * 128, m0 = blockIdx.y * 64, b = blockIdx.z;
  int w = threadIdx.x >> 6, lane = threadIdx.x & 63;
  int g = lane >> 4, q = lane & 15;
  int cw = w >> 1, mw = w & 1;  // c: 2x64, m: 2x32
  const _Float16* vb = vh + (size_t)b * CC * NN;
  const _Float16* pb = PT + (size_t)b * NN * NN;
  int lrow = lane >> 3, lcol = (lane & 7) * 8;

  auto stage = [&](int buf, int k) {
    int n0 = k * 64;
#pragma unroll
    for (int j = 0; j < 6; j++) {
      int blk = j * 4 + w;
      if (blk < 16) {
        int row = blk * 8 + lrow;
        GLOAD16(vb + (size_t)(c0 + row) * NN + n0 + lcol,
                (char*)&Vt[buf][0] + blk * 1024);
      } else {
        int row = (blk - 16) * 8 + lrow;
        GLOAD16(pb + (size_t)(m0 + row) * NN + n0 + lcol,
                (char*)&Pt[buf][0] + (blk - 16) * 1024);
      }
    }
  };

  stage(0, 0);
  __syncthreads();
  fx4 acc[4][2] = {};  // [ct][mt]
  int swz = (q & 7) << 4;
  int cur = 0;
  for (int k = 0; k < 64; k++) {
    if (k < 63) stage(cur ^ 1, k + 1);
    const char* Vb = (const char*)&Vt[cur][0];
    const char* Pb2 = (const char*)&Pt[cur][0];
#pragma unroll
    for (int kt = 0; kt < 2; kt++) {
      int kb = ((kt * 4 + g) << 4) ^ swz;
      h8_t a[4], bb[2];
#pragma unroll
      for (int ct = 0; ct < 4; ct++)
        a[ct] = *(const h8_t*)(Vb + ((cw * 64 + ct * 16 + q) << 7) + kb);
#pragma unroll
      for (int mt = 0; mt < 2; mt++)
        bb[mt] = *(const h8_t*)(Pb2 + ((mw * 32 + mt * 16 + q) << 7) + kb);
#pragma unroll
      for (int ct = 0; ct < 4; ct++)
#pragma unroll
        for (int mt = 0; mt < 2; mt++)
          acc[ct][mt] = MFMA16(a[ct], bb[mt], acc[ct][mt]);
    }
    __syncthreads();
    cur ^= 1;
  }

  float cinv[2];
#pragma unroll
  for (int mt = 0; mt < 2; mt++)
    cinv[mt] = 1.f / (1e-9f + colsum[b * NN + m0 + mw * 32 + mt * 16 + q]);
  const float* xb = x + (size_t)b * CC * NN;
#pragma unroll
  for (int ct = 0; ct < 4; ct++) {
#pragma unroll
    for (int mt = 0; mt < 2; mt++) {
      int m = m0 + mw * 32 + mt * 16 + q;
      int cb = c0 + cw * 64 + ct * 16 + 4 * g;
      h4_t hd;
#pragma unroll
      for (int r = 0; r < 4; r++) {
        float xv = xb[(size_t)(cb + r) * NN + m];
        hd[r] = (_Float16)(xv - acc[ct][mt][r] * cinv[mt]);
      }
      *(h4_t*)&xdT[((size_t)b * NN + m) * CC + cb] = hd;
    }
  }
}

// ---------------- K5: t = wt @ x_d + bt, BN partials ---------------------------
__global__ __launch_bounds__(256, 2) void k5_trans(
    const _Float16* __restrict__ xdT, const _Float16* __restrict__ wtH,
    const float* __restrict__ bt, _Float16* __restrict__ th,
    float* __restrict__ bnsum, float* __restrict__ bnsumsq) {
  __shared__ _Float16 xl[64 * 264];
  int m0 = blockIdx.x * 64, b = blockIdx.y;
  int t = threadIdx.x;
  int w = t >> 6, lane = t & 63, g = lane >> 4, q = lane & 15;
  {
    int row = t >> 2, cb = (t & 3) * 64;
    const _Float16* src = xdT + ((size_t)b * NN + m0 + row) * CC + cb;
#pragma unroll
    for (int j = 0; j < 8; j++)
      *(h8_t*)&xl[row * 264 + cb + j * 8] = *(const h8_t*)(src + j * 8);
  }
  __syncthreads();
  fx4 acc[4][4] = {};  // [ot][mt]
  for (int kt = 0; kt < 8; kt++) {
    h8_t bx[4];
#pragma unroll
    for (int mt = 0; mt < 4; mt++)
      bx[mt] = *(const h8_t*)&xl[(mt * 16 + q) * 264 + kt * 32 + g * 8];
#pragma unroll
    for (int ot = 0; ot < 4; ot++) {
      h8_t a = *(const h8_t*)(wtH + (size_t)(w * 64 + ot * 16 + q) * CC + kt * 32 + g * 8);
#pragma unroll
      for (int mt = 0; mt < 4; mt++)
        acc[ot][mt] = MFMA16(a, bx[mt], acc[ot][mt]);
    }
  }
#pragma unroll
  for (int ot = 0; ot < 4; ot++) {
#pragma unroll
    for (int r = 0; r < 4; r++) {
      int o = w * 64 + ot * 16 + 4 * g + r;
      float btv = bt[o];
      float s1 = 0.f, s2 = 0.f;
#pragma unroll
      for (int mt = 0; mt < 4; mt++) {
        float tv = acc[ot][mt][r] + btv;
        th[((size_t)b * CC + o) * NN + m0 + mt * 16 + q] = (_Float16)tv;
        s1 += tv;
        s2 += tv * tv;
      }
#pragma unroll
      for (int off = 1; off < 16; off <<= 1) {
        s1 += __shfl_xor(s1, off);
        s2 += __shfl_xor(s2, off);
      }
      if (q == 0) {
        atomicAdd(&bnsum[o], s1);
        atomicAdd(&bnsumsq[o], s2);
      }
    }
  }
}

// ---------------- K6: BN finalize (folded) + out = x + relu(sc*t + sh) ---------
__global__ __launch_bounds__(256) void k6_final(
    const float* __restrict__ x, const _Float16* __restrict__ th,
    const float* __restrict__ bnsum, const float* __restrict__ bnsumsq,
    const float* __restrict__ gamma, const float* __restrict__ beta,
    float* __restrict__ out) {
  size_t i = (size_t)blockIdx.x * 256 + threadIdx.x;
  size_t base = i * 8;
  int c = (int)((base >> 12) & 255);
  float inv = 1.f / (float)(BB * NN);
  float mean = bnsum[c] * inv;
  float var = bnsumsq[c] * inv - mean * mean;
  float sc = gamma[c] * rsqrtf(var + 1e-5f);
  float sh = beta[c] - mean * sc;
  h8_t t8 = *(const h8_t*)(th + base);
  fx4 x0 = *(const fx4*)(x + base);
  fx4 x1 = *(const fx4*)(x + base + 4);
  fx4 o0, o1;
#pragma unroll
  for (int j2 = 0; j2 < 4; j2++) {
    o0[j2] = x0[j2] + fmaxf(0.f, sc * (float)t8[j2] + sh);
    o1[j2] = x1[j2] + fmaxf(0.f, sc * (float)t8[j2 + 4] + sh);
  }
  *(fx4*)(out + base) = o0;
  *(fx4*)(out + base + 4) = o1;
}

extern "C" void kernel_launch(void* const* d_in, const int* in_sizes, int n_in,
                              void* d_out, int out_size, void* d_ws, size_t ws_size,
                              hipStream_t stream) {
  const float* x = (const float*)d_in[0];
  const float* wq = (const float*)d_in[1];
  const float* wv = (const float*)d_in[2];
  const float* bv = (const float*)d_in[3];
  const float* wt = (const float*)d_in[4];
  const float* bt = (const float*)d_in[5];
  const float* gamma = (const float*)d_in[6];
  const float* beta = (const float*)d_in[7];
  char* ws = (char*)d_ws;
  _Float16* PT = (_Float16*)(ws + 0);              // 128 MB [b][m][n] swizzled
  _Float16* qh = (_Float16*)(ws + 134217728);      // 2 MB
  _Float16* vh = (_Float16*)(ws + 136314880);      // 8 MB (col-swizzled)
  _Float16* xt = (_Float16*)(ws + 144703488);      // 8 MB
  _Float16* xdT = (_Float16*)(ws + 153092096);     // 8 MB [b][m][c]
  _Float16* th = (_Float16*)(ws + 161480704);      // 8 MB
  _Float16* wqH = (_Float16*)(ws + 169869312);     // 32 KB
  _Float16* wvH = (_Float16*)(ws + 169902080);     // 128 KB
  _Float16* wtH = (_Float16*)(ws + 170033152);     // 128 KB
  float* rowmax = (float*)(ws + 170164224);        // 64 KB
  float* rowsuminv = (float*)(ws + 170229760);     // 64 KB
  float* colsum = (float*)(ws + 170295296);        // 64 KB
  float* bnsum = (float*)(ws + 170360832);         // 1 KB
  float* bnsumsq = (float*)(ws + 170361856);       // 1 KB  (end ~162.5 MiB)

  hipLaunchKernelGGL(k0_prep, dim3(64), dim3(256), 0, stream,
                     wq, wv, wt, wqH, wvH, wtH, bnsum, bnsumsq, colsum);
  hipLaunchKernelGGL(k1a_transpose, dim3(128, 8, 4), dim3(256), 0, stream, x, xt);
  hipLaunchKernelGGL(k1b_proj, dim3(512), dim3(256), 0, stream, xt, wqH, wvH, bv, qh, vh);
  hipLaunchKernelGGL(k2_stats, dim3(512), dim3(512), 0, stream, qh, rowmax, rowsuminv);
  hipLaunchKernelGGL(k3_pmat, dim3(32, 32, 4), dim3(512), 0, stream,
                     qh, rowmax, rowsuminv, PT, colsum);
  hipLaunchKernelGGL(k4_pv, dim3(2, 64, 4), dim3(256), 0, stream,
                     vh, PT, colsum, x, xdT);
  hipLaunchKernelGGL(k5_trans, dim3(64, 4), dim3(256), 0, stream,
                     xdT, wtH, bt, th, bnsum, bnsumsq);
  hipLaunchKernelGGL(k6_final, dim3(2048), dim3(256), 0, stream,
                     x, th, bnsum, bnsumsq, gamma, beta, (float*)d_out);
}